// Round 1
// baseline (11123.253 us; speedup 1.0000x reference)
//
#include <hip/hip_runtime.h>
#include <hip/hip_bf16.h>
#include <stdint.h>

// LSTM: B=32, T=2048, I=256, H=512. torch gate order i,f,g,o.
// Single persistent kernel, 32 blocks x 512 threads; per-step device-scope
// flag barrier; weights resident in VGPRs as MFMA B-fragments.

#define B_   32
#define T_   2048
#define I_   256
#define H_   512
#define NB   32          // recurrent blocks (one per 16 h-columns)
#define NTHR 512         // 8 waves
#define JC   16          // h-columns per block = H_/NB
#define KTOT 768         // H_ + I_ (h then x along K)
#define SA   776         // padded LDS stride (multiple of 8 -> 16B-aligned rows)
#define KSTEPS 24        // KTOT/32

typedef __attribute__((ext_vector_type(8))) short short8;
typedef __attribute__((ext_vector_type(4))) float f32x4;

__device__ __forceinline__ unsigned short f2bf_bits(float v) {
    unsigned int u = __builtin_bit_cast(unsigned int, v);
    unsigned int r = (u + 0x7FFFu + ((u >> 16) & 1u)) >> 16;   // RNE
    return (unsigned short)r;
}
__device__ __forceinline__ float sigm(float x) {
    return 1.0f / (1.0f + __expf(-x));
}
__device__ __forceinline__ float tanh_fast(float x) {
    float e = __expf(2.0f * x);          // inf-safe: e=inf -> 1; e=0 -> -1
    return 1.0f - 2.0f / (e + 1.0f);
}

// Zero the step counters and convert h0 -> bf16 ping buffer. Runs every launch
// (harness re-poisons d_ws with 0xAA before every timed call).
__global__ void lstm_init(const float* __restrict__ h0,
                          unsigned int* __restrict__ cnt,
                          unsigned short* __restrict__ hbuf0) {
    int i = blockIdx.x * 256 + threadIdx.x;
    if (i < T_) cnt[i] = 0u;
    if (i < B_ * H_) hbuf0[i] = f2bf_bits(h0[i]);
}

__global__ __launch_bounds__(NTHR) void lstm_persistent(
    const float* __restrict__ x,    // [B,T,I]
    const float* __restrict__ c0,   // [1,B,H]
    const float* __restrict__ Wih,  // [4H,I]
    const float* __restrict__ Whh,  // [4H,H]
    const float* __restrict__ bih,  // [4H]
    const float* __restrict__ bhh,  // [4H]
    float* __restrict__ out,        // result [B,T,H] ++ h_f [B,H] ++ c_f [B,H]
    unsigned short* __restrict__ hbuf,  // [2][B*H] bf16 ping-pong
    unsigned int* __restrict__ cnt)     // [T] arrival counters
{
    __shared__ __align__(16) unsigned short Als[B_][SA];  // A tile: [m][k] h|x, bf16
    __shared__ float g_ls[B_][4 * JC + 1];                // gate pre-activations
    __shared__ float c_ls[B_][JC];                        // cell state (block-local)
    __shared__ float bias_ls[4 * JC];

    const int tid  = threadIdx.x;
    const int bid  = blockIdx.x;
    const int lane = tid & 63;
    const int wave = tid >> 6;          // 0..7
    const int mi   = (wave & 1) * 16;   // batch-tile base (0 or 16)
    const int q    = wave >> 1;         // gate index 0..3 == n-tile
    const int l15  = lane & 15;
    const int kq8  = (lane >> 4) * 8;   // k sub-block within a 32-wide K step

    // ---- persistent B fragments: B[k][n] = W[row(n)][k], n = l15 ----
    const int grow = q * H_ + bid * JC + l15;   // global gate row
    short8 bfrag[KSTEPS];
#pragma unroll
    for (int s = 0; s < KSTEPS; ++s) {
        const int k0 = s * 32 + kq8;
        short8 f;
#pragma unroll
        for (int j = 0; j < 8; ++j) {
            const int k = k0 + j;
            const float v = (k < H_) ? Whh[(size_t)grow * H_ + k]
                                     : Wih[(size_t)grow * I_ + (k - H_)];
            f[j] = (short)f2bf_bits(v);
        }
        bfrag[s] = f;
    }

    // ---- bias + c0 into LDS ----
    if (tid < 4 * JC) {
        const int qq = tid >> 4, jj = tid & 15;
        const int r = qq * H_ + bid * JC + jj;
        bias_ls[tid] = bih[r] + bhh[r];
    }
    {
        const int b = tid >> 4, jj = tid & 15;
        c_ls[b][jj] = c0[b * H_ + bid * JC + jj];
    }
    __syncthreads();

    for (int t = 0; t < T_; ++t) {
        // stage x_t (independent of h -> overlaps the spin below)
#pragma unroll
        for (int i = 0; i < 4; ++i) {
            const int idx = tid + i * NTHR;           // 0..2047 float4s
            const int m = idx >> 6, k4 = idx & 63;
            const float4 vx = *(const float4*)(x + (size_t)m * T_ * I_ +
                                               (size_t)t * I_ + k4 * 4);
            ushort4 p;
            p.x = f2bf_bits(vx.x); p.y = f2bf_bits(vx.y);
            p.z = f2bf_bits(vx.z); p.w = f2bf_bits(vx.w);
            *(ushort4*)&Als[m][H_ + k4 * 4] = p;
        }

        // wait for every block to publish h_{t} (written at step t-1)
        if (t > 0) {
            if (tid == 0) {
                while (__hip_atomic_load(&cnt[t - 1], __ATOMIC_ACQUIRE,
                                         __HIP_MEMORY_SCOPE_AGENT) < NB) { }
            }
            __syncthreads();
        }

        // stage h (bf16, 32 KB) into LDS
        const unsigned short* hsrc = hbuf + (size_t)(t & 1) * (B_ * H_);
#pragma unroll
        for (int i = 0; i < 4; ++i) {
            const int idx = tid + i * NTHR;           // 0..2047 uint4s
            const int m = idx >> 6, c8 = idx & 63;
            *(uint4*)&Als[m][c8 * 8] = *(const uint4*)(hsrc + m * H_ + c8 * 8);
        }
        __syncthreads();

        // gates[m][n] = sum_k A[m][k] * W[n][k]
        f32x4 acc = {0.f, 0.f, 0.f, 0.f};
        const int mrow = mi + l15;
#pragma unroll
        for (int s = 0; s < KSTEPS; ++s) {
            const short8 a = *(const short8*)&Als[mrow][s * 32 + kq8];
            acc = __builtin_amdgcn_mfma_f32_16x16x32_bf16(a, bfrag[s], acc, 0, 0, 0);
        }
#pragma unroll
        for (int r = 0; r < 4; ++r) {                 // D: col=lane&15, row=(lane>>4)*4+r
            g_ls[mi + (lane >> 4) * 4 + r][q * JC + l15] = acc[r];
        }
        __syncthreads();

        // epilogue: one thread per (batch, column)
        {
            const int b = tid >> 4, jj = tid & 15;
            const float pi = g_ls[b][jj]          + bias_ls[jj];
            const float pf = g_ls[b][JC + jj]     + bias_ls[JC + jj];
            const float pg = g_ls[b][2 * JC + jj] + bias_ls[2 * JC + jj];
            const float po = g_ls[b][3 * JC + jj] + bias_ls[3 * JC + jj];
            const float ig = sigm(pi), fg = sigm(pf);
            const float gg = tanh_fast(pg), og = sigm(po);
            const float c = fg * c_ls[b][jj] + ig * gg;
            c_ls[b][jj] = c;
            const float h = og * tanh_fast(c);
            const int col = bid * JC + jj;
            out[(size_t)b * T_ * H_ + (size_t)t * H_ + col] = h;
            hbuf[(size_t)((t + 1) & 1) * (B_ * H_) + b * H_ + col] =
                f2bf_bits(h);
            if (t == T_ - 1) {
                out[(size_t)B_ * T_ * H_ + b * H_ + col] = h;            // h_f
                out[(size_t)B_ * T_ * H_ + B_ * H_ + b * H_ + col] = c;  // c_f
            }
        }
        __syncthreads();   // drain all waves' stores (vmcnt(0)) before publish
        if (tid == 0) {
            __threadfence();
            __hip_atomic_fetch_add(&cnt[t], 1u, __ATOMIC_RELEASE,
                                   __HIP_MEMORY_SCOPE_AGENT);
        }
    }
}

extern "C" void kernel_launch(void* const* d_in, const int* in_sizes, int n_in,
                              void* d_out, int out_size, void* d_ws, size_t ws_size,
                              hipStream_t stream) {
    const float* x   = (const float*)d_in[0];
    const float* h0  = (const float*)d_in[1];
    const float* c0  = (const float*)d_in[2];
    const float* Wih = (const float*)d_in[3];
    const float* Whh = (const float*)d_in[4];
    const float* bih = (const float*)d_in[5];
    const float* bhh = (const float*)d_in[6];
    float* out = (float*)d_out;

    unsigned int*  cnt  = (unsigned int*)d_ws;                      // 8 KB
    unsigned short* hbuf = (unsigned short*)((char*)d_ws + 8192);   // 64 KB

    hipLaunchKernelGGL(lstm_init, dim3(64), dim3(256), 0, stream, h0, cnt, hbuf);
    hipLaunchKernelGGL(lstm_persistent, dim3(NB), dim3(NTHR), 0, stream,
                       x, c0, Wih, Whh, bih, bhh, out, hbuf, cnt);
}

// Round 2
// 9925.770 us; speedup vs baseline: 1.1206x; 1.1206x over previous
//
#include <hip/hip_runtime.h>
#include <hip/hip_bf16.h>
#include <stdint.h>

// LSTM: B=32, T=2048, I=256, H=512. torch gate order i,f,g,o.
// Single persistent kernel, 32 blocks x 512 threads. Cross-block h exchange
// via agent-scope RELAXED atomics (LLC-coherent sc1 path, no fences); per-block
// monotone flags instead of a contended per-step counter.

#define B_   32
#define T_   2048
#define I_   256
#define H_   512
#define NB   32          // recurrent blocks (one per 16 h-columns)
#define NTHR 512         // 8 waves
#define JC   16          // h-columns per block = H_/NB
#define SA   776         // padded LDS stride (multiple of 8 -> 16B-aligned rows)
#define KSTEPS 24        // (H_+I_)/32

typedef __attribute__((ext_vector_type(8))) short short8;
typedef __attribute__((ext_vector_type(4))) float f32x4;

__device__ __forceinline__ unsigned short f2bf_bits(float v) {
    unsigned int u = __builtin_bit_cast(unsigned int, v);
    unsigned int r = (u + 0x7FFFu + ((u >> 16) & 1u)) >> 16;   // RNE
    return (unsigned short)r;
}
__device__ __forceinline__ float sigm(float x) {
    return 1.0f / (1.0f + __expf(-x));
}
__device__ __forceinline__ float tanh_fast(float x) {
    float e = __expf(2.0f * x);          // inf-safe: e=inf -> 1; e=0 -> -1
    return 1.0f - 2.0f / (e + 1.0f);
}

// Zero the 32 flags and convert h0 -> bf16 ping buffer 0. Runs every launch
// (harness re-poisons d_ws before every timed call).
__global__ void lstm_init(const float* __restrict__ h0,
                          unsigned int* __restrict__ flags,
                          unsigned short* __restrict__ hbuf0) {
    int i = blockIdx.x * 256 + threadIdx.x;
    if (i < NB) flags[i] = 0u;
    if (i < B_ * H_) hbuf0[i] = f2bf_bits(h0[i]);
}

__global__ __launch_bounds__(NTHR) void lstm_persistent(
    const float* __restrict__ x,    // [B,T,I]
    const float* __restrict__ c0,   // [1,B,H]
    const float* __restrict__ Wih,  // [4H,I]
    const float* __restrict__ Whh,  // [4H,H]
    const float* __restrict__ bih,  // [4H]
    const float* __restrict__ bhh,  // [4H]
    float* __restrict__ out,        // result [B,T,H] ++ h_f [B,H] ++ c_f [B,H]
    unsigned int* hbuf,             // [2][B*H/2] packed bf16 pairs (LLC-coherent)
    unsigned int* flags)            // [NB] monotone step flags
{
    __shared__ __align__(16) unsigned short Als[B_][SA];  // A tile: [m][k] h|x
    __shared__ float g_ls[B_][4 * JC + 1];                // gate pre-activations

    const int tid  = threadIdx.x;
    const int bid  = blockIdx.x;
    const int lane = tid & 63;
    const int wave = tid >> 6;          // 0..7
    const int mi   = (wave & 1) * 16;   // batch-tile base (0 or 16)
    const int q    = wave >> 1;         // gate index 0..3 == n-tile
    const int l15  = lane & 15;
    const int kq8  = (lane >> 4) * 8;   // k sub-block within a 32-wide K step

    // ---- persistent B fragments: B[k][n] = W[row(n)][k], n = l15 ----
    const int grow = q * H_ + bid * JC + l15;   // global gate row
    short8 bfrag[KSTEPS];
#pragma unroll
    for (int s = 0; s < KSTEPS; ++s) {
        const int k0 = s * 32 + kq8;
        short8 f;
#pragma unroll
        for (int j = 0; j < 8; ++j) {
            const int k = k0 + j;
            const float v = (k < H_) ? Whh[(size_t)grow * H_ + k]
                                     : Wih[(size_t)grow * I_ + (k - H_)];
            f[j] = (short)f2bf_bits(v);
        }
        bfrag[s] = f;
    }

    // ---- per-thread epilogue state in registers ----
    const int eb   = tid >> 4;          // batch 0..31
    const int ejj  = tid & 15;          // column-in-block 0..15
    const int ecol = bid * JC + ejj;    // global h column
    float bias_i = bih[0 * H_ + ecol] + bhh[0 * H_ + ecol];
    float bias_f = bih[1 * H_ + ecol] + bhh[1 * H_ + ecol];
    float bias_g = bih[2 * H_ + ecol] + bhh[2 * H_ + ecol];
    float bias_o = bih[3 * H_ + ecol] + bhh[3 * H_ + ecol];
    float c_reg  = c0[eb * H_ + ecol];
    __syncthreads();

    for (int t = 0; t < T_; ++t) {
        // ---- stage x_t (independent of h -> overlaps the poll below) ----
#pragma unroll
        for (int i = 0; i < 4; ++i) {
            const int idx = tid + i * NTHR;           // 0..2047 float4s
            const int m = idx >> 6, k4 = idx & 63;
            const float4 vx = *(const float4*)(x + (size_t)m * T_ * I_ +
                                               (size_t)t * I_ + k4 * 4);
            ushort4 p;
            p.x = f2bf_bits(vx.x); p.y = f2bf_bits(vx.y);
            p.z = f2bf_bits(vx.z); p.w = f2bf_bits(vx.w);
            *(ushort4*)&Als[m][H_ + k4 * 4] = p;
        }

        // ---- wait for all blocks to have published h(t) (flag >= t) ----
        if (t > 0) {
            const unsigned tt = (unsigned)t;
            unsigned v;
            do {
                v = __hip_atomic_load(&flags[lane & 31], __ATOMIC_RELAXED,
                                      __HIP_MEMORY_SCOPE_AGENT);
            } while (__ballot(v >= tt) != ~0ull);
            asm volatile("" ::: "memory");
        }

        // ---- stage h(t) from LLC (coalesced u64 atomic loads) ----
        {
            unsigned long long* hsrc =
                (unsigned long long*)(hbuf + (size_t)(t & 1) * (B_ * H_ / 2));
#pragma unroll
            for (int i = 0; i < 8; ++i) {
                const int j = tid + i * NTHR;         // u64 index 0..4095
                const unsigned long long v = __hip_atomic_load(
                    &hsrc[j], __ATOMIC_RELAXED, __HIP_MEMORY_SCOPE_AGENT);
                const int m = j >> 7;                 // 128 u64 per h row
                const int c4 = (j & 127) * 4;         // bf16 column
                *(unsigned long long*)&Als[m][c4] = v;
            }
        }
        __syncthreads();

        // ---- gates[m][n] = sum_k A[m][k] * W[n][k] ----
        f32x4 acc = {0.f, 0.f, 0.f, 0.f};
        const int mrow = mi + l15;
#pragma unroll
        for (int s = 0; s < KSTEPS; ++s) {
            const short8 a = *(const short8*)&Als[mrow][s * 32 + kq8];
            acc = __builtin_amdgcn_mfma_f32_16x16x32_bf16(a, bfrag[s], acc, 0, 0, 0);
        }
#pragma unroll
        for (int r = 0; r < 4; ++r) {                 // D: col=lane&15, row=(lane>>4)*4+r
            g_ls[mi + (lane >> 4) * 4 + r][q * JC + l15] = acc[r];
        }
        __syncthreads();

        // ---- epilogue: one thread per (batch, column) ----
        const float pi = g_ls[eb][ejj]          + bias_i;
        const float pf = g_ls[eb][JC + ejj]     + bias_f;
        const float pg = g_ls[eb][2 * JC + ejj] + bias_g;
        const float po = g_ls[eb][3 * JC + ejj] + bias_o;
        const float ig = sigm(pi), fg = sigm(pf);
        const float gg = tanh_fast(pg), og = sigm(po);
        c_reg = fg * c_reg + ig * gg;
        const float h = og * tanh_fast(c_reg);

        // publish h(t+1): packed bf16 pair, agent-scope atomic (LLC-coherent)
        const unsigned hv = f2bf_bits(h);
        const unsigned nbv = __shfl_xor(hv, 1);
        if ((ejj & 1) == 0) {
            const unsigned word = hv | (nbv << 16);
            __hip_atomic_store(
                &hbuf[(size_t)((t + 1) & 1) * (B_ * H_ / 2) + eb * (H_ / 2) + (ecol >> 1)],
                word, __ATOMIC_RELAXED, __HIP_MEMORY_SCOPE_AGENT);
        }
        asm volatile("s_waitcnt vmcnt(0)" ::: "memory");  // own stores acked at LLC
        __syncthreads();                                   // => all block's stores acked
        if (tid == 0) {
            __hip_atomic_store(&flags[bid], (unsigned)(t + 1), __ATOMIC_RELAXED,
                               __HIP_MEMORY_SCOPE_AGENT);
        }

        // ---- deferred HBM stores (off the recurrence critical path) ----
        out[(size_t)eb * T_ * H_ + (size_t)t * H_ + ecol] = h;
        if (t == T_ - 1) {
            out[(size_t)B_ * T_ * H_ + eb * H_ + ecol] = h;              // h_f
            out[(size_t)B_ * T_ * H_ + B_ * H_ + eb * H_ + ecol] = c_reg; // c_f
        }
    }
}

extern "C" void kernel_launch(void* const* d_in, const int* in_sizes, int n_in,
                              void* d_out, int out_size, void* d_ws, size_t ws_size,
                              hipStream_t stream) {
    const float* x   = (const float*)d_in[0];
    const float* h0  = (const float*)d_in[1];
    const float* c0  = (const float*)d_in[2];
    const float* Wih = (const float*)d_in[3];
    const float* Whh = (const float*)d_in[4];
    const float* bih = (const float*)d_in[5];
    const float* bhh = (const float*)d_in[6];
    float* out = (float*)d_out;

    unsigned int* flags = (unsigned int*)d_ws;                      // 128 B
    unsigned int* hbuf  = (unsigned int*)((char*)d_ws + 4096);      // 64 KB

    hipLaunchKernelGGL(lstm_init, dim3(64), dim3(256), 0, stream,
                       h0, flags, (unsigned short*)hbuf);
    hipLaunchKernelGGL(lstm_persistent, dim3(NB), dim3(NTHR), 0, stream,
                       x, c0, Wih, Whh, bih, bhh, out, hbuf, flags);
}

// Round 3
// 7136.343 us; speedup vs baseline: 1.5587x; 1.3909x over previous
//
#include <hip/hip_runtime.h>
#include <hip/hip_bf16.h>
#include <stdint.h>

// LSTM: B=32, T=2048, I=256, H=512. torch gate order i,f,g,o.
// Single persistent kernel, 32 blocks x 512 threads.
// Cross-block h exchange: each bf16 pair packed with its step tag in ONE
// 64-bit agent-scope relaxed atomic word -> publish is fire-and-forget,
// poll delivers data in the same LLC response. Two-slot ping-pong makes
// exact tag match ABA-safe and poison-proof.

#define B_   32
#define T_   2048
#define I_   256
#define H_   512
#define NB   32          // recurrent blocks (one per 16 h-columns)
#define NTHR 512         // 8 waves
#define JC   16          // h-columns per block = H_/NB
#define SA   776         // padded LDS stride (multiple of 8 -> 16B-aligned rows)
#define KSTEPS 24        // (H_+I_)/32
#define NPAIR (B_ * H_ / 2)   // 8192 u64 words per slot

typedef __attribute__((ext_vector_type(8))) short short8;
typedef __attribute__((ext_vector_type(4))) float f32x4;

__device__ __forceinline__ unsigned short f2bf_bits(float v) {
    unsigned int u = __builtin_bit_cast(unsigned int, v);
    unsigned int r = (u + 0x7FFFu + ((u >> 16) & 1u)) >> 16;   // RNE
    return (unsigned short)r;
}
__device__ __forceinline__ float sigm(float x) {
    return 1.0f / (1.0f + __expf(-x));
}
__device__ __forceinline__ float tanh_fast(float x) {
    float e = __expf(2.0f * x);          // inf-safe: e=inf -> 1; e=0 -> -1
    return 1.0f - 2.0f / (e + 1.0f);
}

// Fill slot 0 with (tag=0, h0 pairs). Slot 1 keeps harness poison — exact
// tag match (poison tag 0xAAAAAAAA != small t) makes that safe.
__global__ void lstm_init(const float* __restrict__ h0,
                          unsigned long long* __restrict__ hbuf0) {
    int i = blockIdx.x * 256 + threadIdx.x;   // pair index 0..NPAIR-1
    if (i < NPAIR) {
        const int b = i >> 8;                 // 256 pairs per batch row
        const int c = (i & 255) * 2;
        const unsigned lo = f2bf_bits(h0[b * H_ + c]);
        const unsigned hi = f2bf_bits(h0[b * H_ + c + 1]);
        const unsigned pair = lo | (hi << 16);
        hbuf0[i] = ((unsigned long long)pair << 32) | 0u;   // tag 0
    }
}

__global__ __launch_bounds__(NTHR) void lstm_persistent(
    const float* __restrict__ x,    // [B,T,I]
    const float* __restrict__ c0,   // [1,B,H]
    const float* __restrict__ Wih,  // [4H,I]
    const float* __restrict__ Whh,  // [4H,H]
    const float* __restrict__ bih,  // [4H]
    const float* __restrict__ bhh,  // [4H]
    float* __restrict__ out,        // result [B,T,H] ++ h_f [B,H] ++ c_f [B,H]
    unsigned long long* hbuf)       // [2][NPAIR] (tag | bf16-pair<<32)
{
    __shared__ __align__(16) unsigned short Als[B_][SA];  // A tile: [m][k] h|x
    __shared__ float g_ls[B_][4 * JC + 1];                // gate pre-activations

    const int tid  = threadIdx.x;
    const int bid  = blockIdx.x;
    const int lane = tid & 63;
    const int wave = tid >> 6;          // 0..7
    const int mi   = (wave & 1) * 16;   // batch-tile base (0 or 16)
    const int q    = wave >> 1;         // gate index 0..3 == n-tile
    const int l15  = lane & 15;
    const int kq8  = (lane >> 4) * 8;   // k sub-block within a 32-wide K step

    // ---- persistent B fragments: B[k][n] = W[row(n)][k], n = l15 ----
    const int grow = q * H_ + bid * JC + l15;   // global gate row
    short8 bfrag[KSTEPS];
#pragma unroll
    for (int s = 0; s < KSTEPS; ++s) {
        const int k0 = s * 32 + kq8;
        short8 f;
#pragma unroll
        for (int j = 0; j < 8; ++j) {
            const int k = k0 + j;
            const float v = (k < H_) ? Whh[(size_t)grow * H_ + k]
                                     : Wih[(size_t)grow * I_ + (k - H_)];
            f[j] = (short)f2bf_bits(v);
        }
        bfrag[s] = f;
    }

    // ---- per-thread epilogue state in registers ----
    const int eb   = tid >> 4;          // batch 0..31
    const int ejj  = tid & 15;          // column-in-block 0..15
    const int ecol = bid * JC + ejj;    // global h column
    float bias_i = bih[0 * H_ + ecol] + bhh[0 * H_ + ecol];
    float bias_f = bih[1 * H_ + ecol] + bhh[1 * H_ + ecol];
    float bias_g = bih[2 * H_ + ecol] + bhh[2 * H_ + ecol];
    float bias_o = bih[3 * H_ + ecol] + bhh[3 * H_ + ecol];
    float c_reg  = c0[eb * H_ + ecol];

    for (int t = 0; t < T_; ++t) {
        // ---- issue x_t loads (HBM latency hides under the poll) ----
        float4 xv[4];
#pragma unroll
        for (int i = 0; i < 4; ++i) {
            const int idx = tid + i * NTHR;           // 0..2047 float4s
            const int m = idx >> 6, k4 = idx & 63;
            xv[i] = *(const float4*)(x + (size_t)m * T_ * I_ +
                                     (size_t)t * I_ + k4 * 4);
        }
        asm volatile("" ::: "memory");   // pin x-load issue before the poll

        // ---- poll h(t): slot t&1, exact tag match delivers the data ----
        const unsigned tt = (unsigned)t;
        unsigned long long* hsrc = hbuf + (size_t)(t & 1) * NPAIR;
        unsigned long long hv[16];
        unsigned need = 0xFFFFu;
        do {
#pragma unroll
            for (int i = 0; i < 16; ++i) {
                if (need & (1u << i)) {
                    hv[i] = __hip_atomic_load(&hsrc[tid + i * NTHR],
                                              __ATOMIC_RELAXED,
                                              __HIP_MEMORY_SCOPE_AGENT);
                }
            }
            unsigned ok = 0;
#pragma unroll
            for (int i = 0; i < 16; ++i)
                if ((unsigned)hv[i] == tt) ok |= (1u << i);
            need &= ~ok;
        } while (need);

        // ---- write h pairs to LDS ----
#pragma unroll
        for (int i = 0; i < 16; ++i) {
            const int j = tid + i * NTHR;             // pair index 0..NPAIR-1
            const int m = j >> 8;                     // 256 pairs per batch
            const int c = (j & 255) * 2;              // bf16 column
            *(unsigned int*)&Als[m][c] = (unsigned int)(hv[i] >> 32);
        }
        // ---- convert & write x to LDS ----
#pragma unroll
        for (int i = 0; i < 4; ++i) {
            const int idx = tid + i * NTHR;
            const int m = idx >> 6, k4 = idx & 63;
            ushort4 p;
            p.x = f2bf_bits(xv[i].x); p.y = f2bf_bits(xv[i].y);
            p.z = f2bf_bits(xv[i].z); p.w = f2bf_bits(xv[i].w);
            *(ushort4*)&Als[m][H_ + k4 * 4] = p;
        }
        __syncthreads();

        // ---- gates[m][n] = sum_k A[m][k] * W[n][k] ----
        f32x4 acc = {0.f, 0.f, 0.f, 0.f};
        const int mrow = mi + l15;
#pragma unroll
        for (int s = 0; s < KSTEPS; ++s) {
            const short8 a = *(const short8*)&Als[mrow][s * 32 + kq8];
            acc = __builtin_amdgcn_mfma_f32_16x16x32_bf16(a, bfrag[s], acc, 0, 0, 0);
        }
#pragma unroll
        for (int r = 0; r < 4; ++r) {                 // D: col=lane&15, row=(lane>>4)*4+r
            g_ls[mi + (lane >> 4) * 4 + r][q * JC + l15] = acc[r];
        }
        __syncthreads();

        // ---- epilogue: one thread per (batch, column) ----
        const float pi = g_ls[eb][ejj]          + bias_i;
        const float pf = g_ls[eb][JC + ejj]     + bias_f;
        const float pg = g_ls[eb][2 * JC + ejj] + bias_g;
        const float po = g_ls[eb][3 * JC + ejj] + bias_o;
        const float ig = sigm(pi), fg = sigm(pf);
        const float gg = tanh_fast(pg), og = sigm(po);
        c_reg = fg * c_reg + ig * gg;
        const float h = og * tanh_fast(c_reg);

        // ---- publish h(t+1): fire-and-forget tagged u64 ----
        const unsigned hvb = f2bf_bits(h);
        const unsigned nbv = __shfl_xor(hvb, 1);
        if ((ejj & 1) == 0) {
            const unsigned pair = hvb | (nbv << 16);
            const unsigned long long word =
                ((unsigned long long)pair << 32) | (unsigned)(t + 1);
            __hip_atomic_store(
                &hbuf[(size_t)((t + 1) & 1) * NPAIR + eb * 256 + (ecol >> 1)],
                word, __ATOMIC_RELAXED, __HIP_MEMORY_SCOPE_AGENT);
        }

        // ---- deferred HBM stores (off the recurrence critical path) ----
        out[(size_t)eb * T_ * H_ + (size_t)t * H_ + ecol] = h;
        if (t == T_ - 1) {
            out[(size_t)B_ * T_ * H_ + eb * H_ + ecol] = h;               // h_f
            out[(size_t)B_ * T_ * H_ + B_ * H_ + eb * H_ + ecol] = c_reg; // c_f
        }
        // No third barrier: next iteration touches Als only, and every wave
        // passed barrier #2 after its last Als read (MFMA ds_reads precede
        // its g_ls write + barrier). g_ls is rewritten only after barrier #1
        // of the next step.
    }
}

extern "C" void kernel_launch(void* const* d_in, const int* in_sizes, int n_in,
                              void* d_out, int out_size, void* d_ws, size_t ws_size,
                              hipStream_t stream) {
    const float* x   = (const float*)d_in[0];
    const float* h0  = (const float*)d_in[1];
    const float* c0  = (const float*)d_in[2];
    const float* Wih = (const float*)d_in[3];
    const float* Whh = (const float*)d_in[4];
    const float* bih = (const float*)d_in[5];
    const float* bhh = (const float*)d_in[6];
    float* out = (float*)d_out;

    unsigned long long* hbuf = (unsigned long long*)d_ws;   // 2*8192*8 = 128 KB

    hipLaunchKernelGGL(lstm_init, dim3(32), dim3(256), 0, stream, h0, hbuf);
    hipLaunchKernelGGL(lstm_persistent, dim3(NB), dim3(NTHR), 0, stream,
                       x, c0, Wih, Whh, bih, bhh, out, hbuf);
}